// Round 4
// baseline (1353.039 us; speedup 1.0000x reference)
//
#include <hip/hip_runtime.h>

// 2-layer LSTM (H=32, D=10, T=512), layer-pipelined:
// threads   0..127: layer-1 gate for timestep k
// threads 128..255: layer-2 gate for timestep k-1 (software wavefront)
// Weights loaded once, then PINNED into VGPRs with asm("" : "+v") so the
// compiler cannot sink/rematerialize the global loads into the t-loop
// (round-2 evidence: VGPR_Count=64 -> weights were being reloaded per iter).

#define HH 32
#define DD 10
#define TT 512

__device__ __forceinline__ float fast_sigmoid(float v) {
    float e = __expf(-v);
    return __builtin_amdgcn_rcpf(1.0f + e);
}
__device__ __forceinline__ float fast_tanh(float v) {
    return fmaf(2.0f, fast_sigmoid(2.0f * v), -1.0f);
}

__global__ __launch_bounds__(256, 4) void lstm2_pin(
    const float* __restrict__ x,
    const float* __restrict__ Wih0, const float* __restrict__ Whh0,
    const float* __restrict__ bih0, const float* __restrict__ bhh0,
    const float* __restrict__ Wih1, const float* __restrict__ Whh1,
    const float* __restrict__ bih1, const float* __restrict__ bhh1,
    const float* __restrict__ Wfc,  const float* __restrict__ bfc,
    float* __restrict__ out)
{
    __shared__ __align__(16) float xs[TT * DD];     // 20480 B
    __shared__ __align__(16) float h1buf[2][HH];
    __shared__ __align__(16) float h2buf[2][HH];
    __shared__ __align__(16) float gl[256];

    const int tid  = threadIdx.x;
    const bool isL1 = tid < 128;
    const int tl   = tid & 127;
    const int j    = tl >> 2;          // hidden unit
    const int q    = tl & 3;           // 0=i 1=f 2=g(tanh) 3=o
    const int row  = q * HH + j;       // row in [4H, *] weight layout

    // ---- stage this batch's x into LDS (coalesced float4) ----
    {
        const float4* src = (const float4*)(x + (size_t)blockIdx.x * TT * DD);
        float4* dst = (float4*)xs;
        #pragma unroll
        for (int i = 0; i < 5; i++) dst[tid + 256 * i] = src[tid + 256 * i];
    }

    // ---- per-role weights ----
    // wB[0..31]: multiplies h1(k-1) in BOTH roles.
    // wA: L1 -> x weights in [0..9], rest zero; L2 -> h2-recurrent weights.
    float wA[HH], wB[HH];
    float bb;
    if (isL1) {
        #pragma unroll
        for (int d = 0; d < DD; d++) wA[d] = Wih0[row * DD + d];
        #pragma unroll
        for (int d = DD; d < HH; d++) wA[d] = 0.0f;
        #pragma unroll
        for (int m = 0; m < HH; m++) wB[m] = Whh0[row * HH + m];
        bb = bih0[row] + bhh0[row];
    } else {
        #pragma unroll
        for (int m = 0; m < HH; m++) wA[m] = Whh1[row * HH + m];
        #pragma unroll
        for (int m = 0; m < HH; m++) wB[m] = Wih1[row * HH + m];
        bb = bih1[row] + bhh1[row];
    }
    // ---- PIN: make each weight opaque so loads can't be rematerialized ----
    #pragma unroll
    for (int m = 0; m < HH; m++) {
        asm("" : "+v"(wA[m]));
        asm("" : "+v"(wB[m]));
    }
    asm("" : "+v"(bb));

    // activation: act(v) = sB * sigmoid(sA*v) + sC   (tanh when q==2)
    const bool is_t = (q == 2);
    const float sA = is_t ? 2.0f : 1.0f;
    const float sB = is_t ? 2.0f : 1.0f;
    const float sC = is_t ? -1.0f : 0.0f;

    if (tid < 64)       (&h1buf[0][0])[tid]      = 0.0f;
    else if (tid < 128) (&h2buf[0][0])[tid - 64] = 0.0f;

    float c = 0.0f;
    __syncthreads();

    for (int k = 0; k <= TT; ++k) {
        const int pr = k & 1;
        const bool active = isL1 ? (k < TT) : (k > 0);
        float a;
        if (active) {
            float acc0 = bb, acc1 = 0.0f;
            if (isL1) {
                const float* xp = &xs[k * DD];
                #pragma unroll
                for (int d = 0; d < DD; d += 2) {
                    float2 v = *(const float2*)(xp + d);     // 8B aligned
                    acc0 = fmaf(wA[d],     v.x, acc0);
                    acc1 = fmaf(wA[d + 1], v.y, acc1);
                }
            } else {
                const float* h2p = &h2buf[pr][0];            // h2(k-2)
                #pragma unroll
                for (int m = 0; m < HH; m += 4) {
                    float4 hv = *(const float4*)(h2p + m);   // uniform bcast
                    acc0 = fmaf(wA[m + 0], hv.x, acc0);
                    acc1 = fmaf(wA[m + 1], hv.y, acc1);
                    acc0 = fmaf(wA[m + 2], hv.z, acc0);
                    acc1 = fmaf(wA[m + 3], hv.w, acc1);
                }
            }
            const float* h1p = &h1buf[pr ^ 1][0];            // h1(k-1)
            #pragma unroll
            for (int m = 0; m < HH; m += 4) {
                float4 hv = *(const float4*)(h1p + m);
                acc0 = fmaf(wB[m + 0], hv.x, acc0);
                acc1 = fmaf(wB[m + 1], hv.y, acc1);
                acc0 = fmaf(wB[m + 2], hv.z, acc0);
                acc1 = fmaf(wB[m + 3], hv.w, acc1);
            }
            a = fmaf(sB, fast_sigmoid(sA * (acc0 + acc1)), sC);
        }

        if (active) {
            gl[tid] = a;
            asm volatile("" ::: "memory");   // order intra-wave LDS write->read
            float4 gv = *(const float4*)&gl[tid & ~3];       // i, f, g~, o
            c = fmaf(gv.y, c, gv.x * gv.z);
            float h = gv.w * fast_tanh(c);
            if (q == 0) {
                if (isL1) h1buf[pr][j]     = h;   // h1(k)   @ parity k&1
                else      h2buf[pr ^ 1][j] = h;   // h2(k-1) @ parity (k-1)&1
            }
        }
        __syncthreads();
    }

    // ---- final FC on h2(T-1) (parity (T-1)&1 == 1) ----
    if (tid == 0) {
        float v = bfc[0];
        #pragma unroll
        for (int m = 0; m < HH; ++m) v = fmaf(h2buf[1][m], Wfc[m], v);
        out[blockIdx.x] = v;
    }
}

extern "C" void kernel_launch(void* const* d_in, const int* in_sizes, int n_in,
                              void* d_out, int out_size, void* d_ws, size_t ws_size,
                              hipStream_t stream) {
    const float* x    = (const float*)d_in[0];
    const float* Wih0 = (const float*)d_in[1];
    const float* Whh0 = (const float*)d_in[2];
    const float* bih0 = (const float*)d_in[3];
    const float* bhh0 = (const float*)d_in[4];
    const float* Wih1 = (const float*)d_in[5];
    const float* Whh1 = (const float*)d_in[6];
    const float* bih1 = (const float*)d_in[7];
    const float* bhh1 = (const float*)d_in[8];
    const float* Wfc  = (const float*)d_in[9];
    const float* bfc  = (const float*)d_in[10];
    float* out = (float*)d_out;

    const int B = in_sizes[0] / (TT * DD);   // 4096
    dim3 grid(B), block(256);
    hipLaunchKernelGGL(lstm2_pin, grid, block, 0, stream,
                       x, Wih0, Whh0, bih0, bhh0,
                       Wih1, Whh1, bih1, bhh1, Wfc, bfc, out);
}